// Round 12
// baseline (2072.143 us; speedup 1.0000x reference)
//
#include <hip/hip_runtime.h>
#include <hip/hip_bf16.h>

typedef __hip_bfloat16 bf16;
typedef __attribute__((ext_vector_type(8))) short bf16x8;
typedef __attribute__((ext_vector_type(4))) float f32x4;
typedef __attribute__((ext_vector_type(4))) int i32x4;

#define HH 300     // hidden
#define NMOLS 2000
#define AFD 133    // atom feature dim
#define BFD 147    // bond feature dim
#define KP 480     // padded K of WT buffers (15 steps of 32)
#define GOFS 160   // tail region starts at k=160 (step 5)
#define NWT (320 * KP)
#define FBP 160    // padded bf16 feature row length

// ---- direct global->LDS: dest = wave-uniform base + lane*16 ----
__device__ inline void gll16(short* lds_base, const void* gsrc) {
  auto l = (__attribute__((address_space(3))) short*)lds_base;
  auto g = (const __attribute__((address_space(1))) char*)gsrc;
  __builtin_amdgcn_global_load_lds(g, l, 16, 0, 0);
}

__device__ inline void vwait(int n) {
  switch (n) {
    case 5: asm volatile("s_waitcnt vmcnt(5)" ::: "memory"); break;
    case 6: asm volatile("s_waitcnt vmcnt(6)" ::: "memory"); break;
    default: asm volatile("s_waitcnt vmcnt(7)" ::: "memory"); break;
  }
}

// ---- build WT[c][k] bf16: k<fd -> W0[k][c]; 160<=k<460 -> W1[k-160][c]; else 0 ----
// Zero pads load-bearing: A-tail overruns rows; products hit WT==0.
__global__ void build_wt(const float* __restrict__ W0, const float* __restrict__ W1,
                         int fd, bf16* __restrict__ WT)
{
  int idx = blockIdx.x * 256 + threadIdx.x;
  if (idx >= NWT) return;
  int c = idx / KP, k = idx - c * KP;
  float v = 0.f;
  if (c < HH) {
    if (k < fd) v = W0[(size_t)k * HH + c];
    else if (k >= GOFS && k < GOFS + HH) v = W1[(size_t)(k - GOFS) * HH + c];
  }
  WT[idx] = __float2bfloat16(v);
}

// ---- pad/convert features: Y[r][0..159] = bf16(X[r][0..fd-1]) | zeros ----
__global__ __launch_bounds__(256)
void cvt_pad(const float* __restrict__ X, int fd, bf16* __restrict__ Y, int N)
{
  int idx = blockIdx.x * 256 + threadIdx.x;
  if (idx >= N * 20) return;
  int rr = idx / 20, c8 = (idx - rr * 20) * 8;
  short t[8];
#pragma unroll
  for (int j = 0; j < 8; j++) {
    int c = c8 + j;
    float v = (c < fd) ? X[(size_t)rr * fd + c] : 0.f;
    union { bf16 b; short s; } cv; cv.b = __float2bfloat16(v); t[j] = cv.s;
  }
  *(bf16x8*)(Y + (size_t)rr * FBP + c8) = *(const bf16x8*)t;
}

// ---- amsg[a][k] = sum_j msg[a2b[a][j]][k]; 8 elems/thread ----
__global__ __launch_bounds__(256)
void gather6_k(const bf16* __restrict__ msg, const int* __restrict__ a2b,
               bf16* __restrict__ amsg, int A)
{
  int idx = blockIdx.x * 256 + threadIdx.x;
  if (idx >= A * 38) return;
  int a = idx / 38;
  int k8 = (idx - a * 38) * 8;
  const int* p = a2b + (size_t)a * 6;
  uint2 u0[6], u1[6];
#pragma unroll
  for (int j = 0; j < 6; j++) {
    const bf16* q = msg + (size_t)p[j] * HH + k8;
    u0[j] = *(const uint2*)q;
    u1[j] = *(const uint2*)(q + 4);   // may cross row end; pad-safe, unused
  }
  float s[8] = {0.f,0.f,0.f,0.f,0.f,0.f,0.f,0.f};
#pragma unroll
  for (int j = 0; j < 6; j++) {
    unsigned w[4] = {u0[j].x, u0[j].y, u1[j].x, u1[j].y};
#pragma unroll
    for (int q2 = 0; q2 < 4; q2++) {
      union { unsigned u; float f; } lo, hi;
      lo.u = w[q2] << 16;
      hi.u = w[q2] & 0xffff0000u;
      s[2 * q2]     += lo.f;
      s[2 * q2 + 1] += hi.f;
    }
  }
  short t[8];
#pragma unroll
  for (int j = 0; j < 8; j++) {
    union { bf16 b; short sh; } cv; cv.b = __float2bfloat16(s[j]); t[j] = cv.sh;
  }
  bf16* dst = amsg + (size_t)a * HH + k8;
  *(uint2*)dst = *(const uint2*)t;
  if (k8 + 8 <= HH) *(uint2*)((short*)dst + 4) = *(const uint2*)(t + 4);
}

// ============ gll-staged MFMA GEMM: 64 rows x 320 cols, 8 waves (512 thr) ============
// Per wave: 32 rows x 80 cols, acc[2][5] (40 AGPR) -> ~125 unified regs -> 16 waves/CU.
// Staging: MODE1: waves 0-3 stage As (amsg side), waves 4-7 stage Ms (msg side);
// MODE0/2: waves 0-3 stage As, waves 4-7 idle (skip vwait; barrier publishes LDS).
// Ring D=3; counted vmcnt (never 0); B-frags double-buffered in registers.
// MODE 0: C = fbb@Wi (5 steps);                          msg = relu(C), row0=0
// MODE 1: C = fbb@Wi + amsg[b2a]@Wh + (-msg[b2revb])@Wh; msg = relu(C), row0=0
// MODE 2: C = [fab | amsg]@Wo;                           hid = relu(C + bias)
template<int MODE>
__global__ __launch_bounds__(512, 4)
void gemm_g(const bf16* __restrict__ FB, const bf16* __restrict__ WT,
            const int* __restrict__ b2a, const int* __restrict__ b2revb,
            const bf16* __restrict__ amsg, const bf16* __restrict__ msgc,
            const float* __restrict__ bias,
            bf16* __restrict__ msg_out, float* __restrict__ hid_out, int M)
{
  constexpr int KSTEPS = (MODE == 0) ? 5 : 15;
  constexpr bool DUAL = (MODE == 1);
  constexpr int D = 3;

  __shared__ __align__(16) short As[D][2048];           // 64 rows x 32 k per slot
  __shared__ __align__(16) short Ms[DUAL ? D : 1][2048];

  const int tid = threadIdx.x;
  const int lane = tid & 63;
  const int wave = tid >> 6;          // 0..7
  const int gm0 = blockIdx.x * 64;

  // ---- staging role ----
  const bool isA = wave < 4;          // As-stager vs Ms-stager (MODE1)
  const bool stages = DUAL || isA;    // MODE0/2: waves 4-7 idle
  const int sw = wave & 3;            // staging slot 0..3 (16 rows each)
  const int lrow = sw * 16 + (lane >> 2);
  const int ssl = (lane & 3) ^ ((lrow >> 1) & 3);   // source-side k-chunk swizzle
  const int grow = min(gm0 + lrow, M - 1);          // clamped (stores guarded)
  int gidx = grow;
  if constexpr (DUAL) gidx = isA ? b2a[grow] : b2revb[grow];

  // ---- compute role: wave -> (row group, col group) ----
  const int rg = wave >> 2;           // 0..1 (32-row half)
  const int cg = wave & 3;            // 0..3 (80-col group)
  const int r = lane & 15, q = lane >> 4;
  int aoff[2];
#pragma unroll
  for (int i = 0; i < 2; i++) {
    int rr = rg * 32 + i * 16 + r;
    aoff[i] = rr * 32 + ((q ^ (rr >> 1)) & 3) * 8;
  }
  const bf16* bb = WT + (size_t)(cg * 80 + r) * KP + q * 8;

  f32x4 acc[2][5];
#pragma unroll
  for (int i = 0; i < 2; i++)
#pragma unroll
    for (int j = 0; j < 5; j++) acc[i][j] = (f32x4){0.f, 0.f, 0.f, 0.f};

  bf16x8 bufB[2][5];
  auto issueB = [&](int s) {
#pragma unroll
    for (int j = 0; j < 5; j++)
      bufB[s & 1][j] = *(const bf16x8*)(bb + (size_t)j * 16 * KP + s * 32);
  };

  auto issueG = [&](int s) {
    if (!stages) return;
    short* dst = isA ? &As[s % D][sw * 512] : &Ms[s % D][sw * 512];
    const bf16* src;
    if (s < 5 && MODE != 1) {
      src = FB + (size_t)grow * FBP + s * 32 + ssl * 8;
      if (MODE == 2) { /* features */ }
    } else if constexpr (MODE == 1) {
      if (s < 5) src = FB + (size_t)grow * FBP + s * 32 + ssl * 8;  // both sides load FB (Ms copy unused pre-tail; keeps vmcnt uniform)
      else       src = (isA ? amsg + (size_t)gidx * HH : msgc + (size_t)gidx * HH)
                       + (s - 5) * 32 + ssl * 8;
    } else {  // MODE 2 tail
      src = amsg + (size_t)grow * HH + (s - 5) * 32 + ssl * 8;
    }
    gll16(dst, src);
  };

  auto computeS = [&](int s) {
    const short* ca = &As[s % D][0];
    bf16x8 af[2];
#pragma unroll
    for (int i = 0; i < 2; i++) af[i] = *(const bf16x8*)(ca + aoff[i]);
#pragma unroll
    for (int j = 0; j < 5; j++)
#pragma unroll
      for (int i = 0; i < 2; i++)
        acc[i][j] = __builtin_amdgcn_mfma_f32_16x16x32_bf16(af[i], bufB[s & 1][j], acc[i][j], 0, 0, 0);
    if constexpr (DUAL) {
      if (s >= 5) {
        const short* cm = &Ms[s % D][0];
        bf16x8 mfn[2];
#pragma unroll
        for (int i = 0; i < 2; i++) {
          union { bf16x8 h; i32x4 w; } u;
          u.h = *(const bf16x8*)(cm + aoff[i]);
          u.w = u.w ^ (int)0x80008000;    // bf16 sign-flip: (-msg)@Wh
          mfn[i] = u.h;
        }
#pragma unroll
        for (int j = 0; j < 5; j++)
#pragma unroll
          for (int i = 0; i < 2; i++)
            acc[i][j] = __builtin_amdgcn_mfma_f32_16x16x32_bf16(mfn[i], bufB[s & 1][j], acc[i][j], 0, 0, 0);
      }
    }
  };

  // ---- prologue: G(0), G(1), B(0)  (B after G: ledger exact) ----
  issueG(0);
  issueG(1);
  issueB(0);
  __builtin_amdgcn_sched_barrier(0);

  // ---- main loop. Per-wave ledger (stagers, 1 gll/step): ops newer than G(s)
  //      = {B(s)=5, G(s+1)=1} -> vmcnt(6); last step -> vmcnt(5). Non-stagers
  //      (MODE0/2 waves 4-7) skip the wait; barrier publishes stagers' LDS. ----
#pragma unroll
  for (int s = 0; s < KSTEPS; s++) {
    if (stages) vwait(s == KSTEPS - 1 ? 5 : 6);
    __builtin_amdgcn_s_barrier();
    __builtin_amdgcn_sched_barrier(0);
    if (s + 1 < KSTEPS) issueB(s + 1);
    if (s + 2 < KSTEPS) issueG(s + 2);
    __builtin_amdgcn_sched_barrier(0);
    computeS(s);
  }

  // ---- epilogue: C/D frag col=lane&15, row=(lane>>4)*4+reg ----
#pragma unroll
  for (int j = 0; j < 5; j++) {
    int c = cg * 80 + j * 16 + r;
    if (c >= HH) continue;
    float bia = (MODE == 2) ? bias[c] : 0.f;
#pragma unroll
    for (int i = 0; i < 2; i++) {
#pragma unroll
      for (int ri = 0; ri < 4; ri++) {
        int g = gm0 + rg * 32 + i * 16 + q * 4 + ri;
        if (g >= M) continue;
        float v = acc[i][j][ri];
        if (MODE == 2) {
          hid_out[(size_t)g * HH + c] = fmaxf(v + bia, 0.f);
        } else {
          float rv = fmaxf(v, 0.f);
          if (g == 0) rv = 0.f;
          msg_out[(size_t)g * HH + c] = __float2bfloat16(rv);
        }
      }
    }
  }
}

// per-molecule mean over sorted mol_id (binary search, no atomics)
__global__ void readout_k(const float* __restrict__ hid, const int* __restrict__ mol_id,
                          float* __restrict__ out, int A)
{
  __shared__ int bnd[2];
  int m = blockIdx.x;
  if (threadIdx.x < 2) {
    int target = m + (int)threadIdx.x;
    int lo = 0, hi = A;
    while (lo < hi) { int mid = (lo + hi) >> 1; if (mol_id[mid] < target) lo = mid + 1; else hi = mid; }
    bnd[threadIdx.x] = lo;
  }
  __syncthreads();
  int s = bnd[0], e = bnd[1];
  int h = threadIdx.x;
  if (h >= HH) return;
  float acc = 0.f;
  for (int a = s; a < e; a++) acc += hid[(size_t)a * HH + h];
  int cnt = e - s; if (cnt < 1) cnt = 1;
  out[(size_t)m * HH + h] = acc / (float)cnt;
}

extern "C" void kernel_launch(void* const* d_in, const int* in_sizes, int n_in,
                              void* d_out, int out_size, void* d_ws, size_t ws_size,
                              hipStream_t stream)
{
  const float* f_atoms[2] = {(const float*)d_in[0], (const float*)d_in[2]};
  const float* f_bonds[2] = {(const float*)d_in[1], (const float*)d_in[3]};
  const float* W_i[2]     = {(const float*)d_in[4], (const float*)d_in[5]};
  const float* W_h[2]     = {(const float*)d_in[6], (const float*)d_in[7]};
  const float* W_o[2]     = {(const float*)d_in[8], (const float*)d_in[10]};
  const float* b_o[2]     = {(const float*)d_in[9], (const float*)d_in[11]};
  const int* a2b[2]    = {(const int*)d_in[12], (const int*)d_in[16]};
  const int* b2a[2]    = {(const int*)d_in[13], (const int*)d_in[17]};
  const int* b2revb[2] = {(const int*)d_in[14], (const int*)d_in[18]};
  const int* mol_id[2] = {(const int*)d_in[15], (const int*)d_in[19]};
  const int A = in_sizes[0] / AFD;   // 100001
  const int B = in_sizes[1] / BFD;   // 200001

  // ws: M0 | M1/hid | amsg | fbb | fab | 4x WT   (~397 MB; proven fits)
  auto al = [](size_t x){ return (x + 255) & ~(size_t)255; };
  size_t r0 = al((size_t)B * HH * sizeof(bf16));
  size_t r1sz = (size_t)B * HH * sizeof(bf16);
  size_t hsz  = (size_t)A * HH * sizeof(float);
  size_t r1 = al(r1sz > hsz ? r1sz : hsz);
  size_t amsz = al((size_t)A * HH * sizeof(bf16));
  size_t fbbsz = al((size_t)B * FBP * sizeof(bf16));
  size_t fabsz = al((size_t)A * FBP * sizeof(bf16));
  size_t wtsz = al((size_t)NWT * sizeof(bf16));
  if (ws_size < r0 + r1 + amsz + fbbsz + fabsz + 4 * wtsz) return;

  char* ws = (char*)d_ws;
  bf16*  M0  = (bf16*)ws;
  bf16*  M1  = (bf16*)(ws + r0);
  float* hid = (float*)(ws + r0);
  bf16*  amsg = (bf16*)(ws + r0 + r1);
  bf16*  fbb  = (bf16*)(ws + r0 + r1 + amsz);
  bf16*  fab  = (bf16*)(ws + r0 + r1 + amsz + fbbsz);
  size_t wofs = r0 + r1 + amsz + fbbsz + fabsz;
  bf16* WT1[2] = {(bf16*)(ws + wofs),            (bf16*)(ws + wofs + wtsz)};
  bf16* WT2[2] = {(bf16*)(ws + wofs + 2 * wtsz), (bf16*)(ws + wofs + 3 * wtsz)};

  dim3 blk(256), blk512(512);
  dim3 gW((NWT + 255) / 256);
  dim3 gB((B + 63) / 64);
  dim3 gA((A + 63) / 64);
  dim3 gG((A * 38 + 255) / 256);

  for (int p = 0; p < 2; p++) {
    build_wt<<<gW, blk, 0, stream>>>(W_i[p], W_h[p], BFD, WT1[p]);
    build_wt<<<gW, blk, 0, stream>>>(W_o[p], W_o[p] + (size_t)AFD * HH, AFD, WT2[p]);
  }

  for (int p = 0; p < 2; p++) {
    float* out_p = (float*)d_out + (size_t)p * NMOLS * HH;
    cvt_pad<<<(B * 20 + 255) / 256, blk, 0, stream>>>(f_bonds[p], BFD, fbb, B);
    cvt_pad<<<(A * 20 + 255) / 256, blk, 0, stream>>>(f_atoms[p], AFD, fab, A);
    // msg(M0) = relu(fbb @ W_i), row0=0
    gemm_g<0><<<gB, blk512, 0, stream>>>(fbb, WT1[p], nullptr, nullptr,
                                         nullptr, nullptr, nullptr, M0, nullptr, B);
    // iter 1: amsg = gather6(M0); M1 = relu(fbb@Wi + amsg[b2a]@Wh - M0[b2revb]@Wh)
    gather6_k<<<gG, blk, 0, stream>>>(M0, a2b[p], amsg, A);
    gemm_g<1><<<gB, blk512, 0, stream>>>(fbb, WT1[p], b2a[p], b2revb[p],
                                         amsg, M0, nullptr, M1, nullptr, B);
    // iter 2
    gather6_k<<<gG, blk, 0, stream>>>(M1, a2b[p], amsg, A);
    gemm_g<1><<<gB, blk512, 0, stream>>>(fbb, WT1[p], b2a[p], b2revb[p],
                                         amsg, M1, nullptr, M0, nullptr, B);
    // output layer
    gather6_k<<<gG, blk, 0, stream>>>(M0, a2b[p], amsg, A);
    gemm_g<2><<<gA, blk512, 0, stream>>>(fab, WT2[p], nullptr, nullptr,
                                         amsg, nullptr, b_o[p], nullptr, hid, A);
    // per-molecule mean readout
    readout_k<<<NMOLS, 320, 0, stream>>>(hid, mol_id[p], out_p, A);
  }
}

// Round 13
// 1787.976 us; speedup vs baseline: 1.1589x; 1.1589x over previous
//
#include <hip/hip_runtime.h>
#include <hip/hip_bf16.h>

typedef __hip_bfloat16 bf16;
typedef __attribute__((ext_vector_type(8))) short bf16x8;
typedef __attribute__((ext_vector_type(4))) float f32x4;
typedef __attribute__((ext_vector_type(4))) int i32x4;

#define HH 300     // hidden
#define NMOLS 2000
#define AFD 133    // atom feature dim
#define BFD 147    // bond feature dim
#define KP 480     // padded K of WT buffers (15 steps of 32)
#define GOFS 160   // tail region starts at k=160 (step 5)
#define NWT (320 * KP)
#define FBP 160    // padded bf16 feature row length

// ---- direct global->LDS: dest = wave-uniform base + lane*16 ----
__device__ inline void gll16(short* lds_base, const void* gsrc) {
  auto l = (__attribute__((address_space(3))) short*)lds_base;
  auto g = (const __attribute__((address_space(1))) char*)gsrc;
  __builtin_amdgcn_global_load_lds(g, l, 16, 0, 0);
}

// counted vmcnt; cases cover every value newerCnt can produce; default = full
// drain (conservative -> correctness never depends on constant folding)
__device__ __forceinline__ void vwait(int n) {
  switch (n) {
    case 10: asm volatile("s_waitcnt vmcnt(10)" ::: "memory"); break;
    case 13: asm volatile("s_waitcnt vmcnt(13)" ::: "memory"); break;
    case 16: asm volatile("s_waitcnt vmcnt(16)" ::: "memory"); break;
    case 17: asm volatile("s_waitcnt vmcnt(17)" ::: "memory"); break;
    case 18: asm volatile("s_waitcnt vmcnt(18)" ::: "memory"); break;
    case 19: asm volatile("s_waitcnt vmcnt(19)" ::: "memory"); break;
    case 21: asm volatile("s_waitcnt vmcnt(21)" ::: "memory"); break;
    case 22: asm volatile("s_waitcnt vmcnt(22)" ::: "memory"); break;
    case 23: asm volatile("s_waitcnt vmcnt(23)" ::: "memory"); break;
    case 26: asm volatile("s_waitcnt vmcnt(26)" ::: "memory"); break;
    case 28: asm volatile("s_waitcnt vmcnt(28)" ::: "memory"); break;
    case 31: asm volatile("s_waitcnt vmcnt(31)" ::: "memory"); break;
    default: asm volatile("s_waitcnt vmcnt(0)"  ::: "memory"); break;
  }
}

// Per-wave VMEM issue schedule (batches, in order):
//   prologue: G(0) G(1) G(2) G(3) B(0) B(1)
//   iter u:   [vwait][barrier] B(u+2) G(u+4) compute(u)
// B batch = 5 loads; G batch = NG glls. vmcnt retires in issue order, so
// waiting "outstanding <= #ops issued after G(s)" guarantees G(s) landed.
__device__ __forceinline__ int newerCnt(int s, int K, int NG) {
  int posGs = (s <= 3) ? s : 7 + 2 * (s - 4);
  int W = 6 + 2 * s;                    // wait point = start of iter s
  int n = 0;
  for (int t = 0; t < K; t++) {
    int pb = (t <= 1) ? (4 + t) : (6 + 2 * (t - 2));
    int pg = (t <= 3) ? t : (7 + 2 * (t - 4));
    if (pb > posGs && pb < W) n += 5;
    if (pg > posGs && pg < W) n += NG;
  }
  return n;
}

// ---- build WT[c][k] bf16: k<fd -> W0[k][c]; 160<=k<460 -> W1[k-160][c]; else 0 ----
// Zero pads load-bearing: A-tail overruns rows; products hit WT==0.
__global__ void build_wt(const float* __restrict__ W0, const float* __restrict__ W1,
                         int fd, bf16* __restrict__ WT)
{
  int idx = blockIdx.x * 256 + threadIdx.x;
  if (idx >= NWT) return;
  int c = idx / KP, k = idx - c * KP;
  float v = 0.f;
  if (c < HH) {
    if (k < fd) v = W0[(size_t)k * HH + c];
    else if (k >= GOFS && k < GOFS + HH) v = W1[(size_t)(k - GOFS) * HH + c];
  }
  WT[idx] = __float2bfloat16(v);
}

// ---- pad/convert features: Y[r][0..159] = bf16(X[r][0..fd-1]) | zeros ----
__global__ __launch_bounds__(256)
void cvt_pad(const float* __restrict__ X, int fd, bf16* __restrict__ Y, int N)
{
  int idx = blockIdx.x * 256 + threadIdx.x;
  if (idx >= N * 20) return;
  int rr = idx / 20, c8 = (idx - rr * 20) * 8;
  short t[8];
#pragma unroll
  for (int j = 0; j < 8; j++) {
    int c = c8 + j;
    float v = (c < fd) ? X[(size_t)rr * fd + c] : 0.f;
    union { bf16 b; short s; } cv; cv.b = __float2bfloat16(v); t[j] = cv.s;
  }
  *(bf16x8*)(Y + (size_t)rr * FBP + c8) = *(const bf16x8*)t;
}

// ---- amsg[a][k] = sum_j msg[a2b[a][j]][k]; 8 elems/thread ----
__global__ __launch_bounds__(256)
void gather6_k(const bf16* __restrict__ msg, const int* __restrict__ a2b,
               bf16* __restrict__ amsg, int A)
{
  int idx = blockIdx.x * 256 + threadIdx.x;
  if (idx >= A * 38) return;
  int a = idx / 38;
  int k8 = (idx - a * 38) * 8;
  const int* p = a2b + (size_t)a * 6;
  uint2 u0[6], u1[6];
#pragma unroll
  for (int j = 0; j < 6; j++) {
    const bf16* q = msg + (size_t)p[j] * HH + k8;
    u0[j] = *(const uint2*)q;
    u1[j] = *(const uint2*)(q + 4);   // may cross row end; pad-safe, unused
  }
  float s[8] = {0.f,0.f,0.f,0.f,0.f,0.f,0.f,0.f};
#pragma unroll
  for (int j = 0; j < 6; j++) {
    unsigned w[4] = {u0[j].x, u0[j].y, u1[j].x, u1[j].y};
#pragma unroll
    for (int q2 = 0; q2 < 4; q2++) {
      union { unsigned u; float f; } lo, hi;
      lo.u = w[q2] << 16;
      hi.u = w[q2] & 0xffff0000u;
      s[2 * q2]     += lo.f;
      s[2 * q2 + 1] += hi.f;
    }
  }
  short t[8];
#pragma unroll
  for (int j = 0; j < 8; j++) {
    union { bf16 b; short sh; } cv; cv.b = __float2bfloat16(s[j]); t[j] = cv.sh;
  }
  bf16* dst = amsg + (size_t)a * HH + k8;
  *(uint2*)dst = *(const uint2*)t;
  if (k8 + 8 <= HH) *(uint2*)((short*)dst + 4) = *(const uint2*)(t + 4);
}

// ============ gll-staged MFMA GEMM: 64 rows x 320 cols, 4 waves split N ============
// r11 structure, deepened: gll ring D=5 (prefetch distance 4 covers ~1000cy HBM),
// B-frag ring of 3 (distance 2 covers L2). Counted vmcnt per exact ledger.
// MODE 0: C = fbb@Wi (5 steps);                          msg = relu(C), row0=0
// MODE 1: C = fbb@Wi + amsg[b2a]@Wh + (-msg[b2revb])@Wh; msg = relu(C), row0=0
// MODE 2: C = [fab | amsg]@Wo;                           hid = relu(C + bias)
template<int MODE>
__global__ __launch_bounds__(256)
void gemm_g(const bf16* __restrict__ FB, const bf16* __restrict__ WT,
            const int* __restrict__ b2a, const int* __restrict__ b2revb,
            const bf16* __restrict__ amsg, const bf16* __restrict__ msgc,
            const float* __restrict__ bias,
            bf16* __restrict__ msg_out, float* __restrict__ hid_out, int M)
{
  constexpr int KSTEPS = (MODE == 0) ? 5 : 15;
  constexpr bool DUAL = (MODE == 1);
  constexpr int D = 5;
  constexpr int NG = DUAL ? 2 : 1;   // glls per wave per step

  __shared__ __align__(16) short As[D][2048];           // 64 rows x 32 k per slot
  __shared__ __align__(16) short Ms[DUAL ? D : 1][2048];

  const int tid = threadIdx.x;
  const int lane = tid & 63;
  const int wave = tid >> 6;
  const int gm0 = blockIdx.x * 64;

  // staging map: wave stages rows [wave*16, wave*16+16); LDS dest linear (gll),
  // swizzle applied on SOURCE k-chunk; read side applies same XOR.
  const int lrow = wave * 16 + (lane >> 2);
  const int ssl = (lane & 3) ^ ((lrow >> 1) & 3);
  const int grow = min(gm0 + lrow, M - 1);   // clamped (stores guarded)
  int ba = 0, rb = 0;
  if constexpr (DUAL) { ba = b2a[grow]; rb = b2revb[grow]; }

  // compute map
  const int r = lane & 15, q = lane >> 4;
  int aoff[4];
#pragma unroll
  for (int i = 0; i < 4; i++) {
    int rr = i * 16 + r;
    aoff[i] = rr * 32 + ((q ^ (rr >> 1)) & 3) * 8;
  }
  const bf16* bb = WT + (size_t)(wave * 80 + r) * KP + q * 8;

  f32x4 acc[4][5];
#pragma unroll
  for (int i = 0; i < 4; i++)
#pragma unroll
    for (int j = 0; j < 5; j++) acc[i][j] = (f32x4){0.f, 0.f, 0.f, 0.f};

  bf16x8 bufB[3][5];                 // ring of 3, distance-2 prefetch
  auto issueB = [&](int s) {
#pragma unroll
    for (int j = 0; j < 5; j++)
      bufB[s % 3][j] = *(const bf16x8*)(bb + (size_t)j * 16 * KP + s * 32);
  };

  auto issueG = [&](int s) {
    short* la = &As[s % D][wave * 512];
    if constexpr (MODE == 0) {
      gll16(la, FB + (size_t)grow * FBP + s * 32 + ssl * 8);
    } else if constexpr (MODE == 2) {
      if (s < 5) gll16(la, FB + (size_t)grow * FBP + s * 32 + ssl * 8);
      else       gll16(la, amsg + (size_t)grow * HH + (s - 5) * 32 + ssl * 8);
    } else {
      short* lm = &Ms[s % D][wave * 512];
      if (s < 5) {
        const bf16* src = FB + (size_t)grow * FBP + s * 32 + ssl * 8;
        gll16(la, src);
        gll16(lm, src);   // duplicate: keeps per-step gll count uniform (ledger)
      } else {
        int kk = (s - 5) * 32 + ssl * 8;
        gll16(la, amsg + (size_t)ba * HH + kk);
        gll16(lm, msgc + (size_t)rb * HH + kk);
      }
    }
  };

  auto computeS = [&](int s) {
    const short* ca = &As[s % D][0];
    bf16x8 af[4];
#pragma unroll
    for (int i = 0; i < 4; i++) af[i] = *(const bf16x8*)(ca + aoff[i]);
    bf16x8 mfn[4];
    if constexpr (DUAL) {
      if (s >= 5) {
        const short* cm = &Ms[s % D][0];
#pragma unroll
        for (int i = 0; i < 4; i++) {
          union { bf16x8 h; i32x4 w; } u;
          u.h = *(const bf16x8*)(cm + aoff[i]);
          u.w = u.w ^ (int)0x80008000;    // bf16 sign-flip: (-msg)@Wh
          mfn[i] = u.h;
        }
      }
    }
#pragma unroll
    for (int j = 0; j < 5; j++)
#pragma unroll
      for (int i = 0; i < 4; i++) {
        acc[i][j] = __builtin_amdgcn_mfma_f32_16x16x32_bf16(af[i], bufB[s % 3][j], acc[i][j], 0, 0, 0);
        if constexpr (DUAL) {
          if (s >= 5)
            acc[i][j] = __builtin_amdgcn_mfma_f32_16x16x32_bf16(mfn[i], bufB[s % 3][j], acc[i][j], 0, 0, 0);
        }
      }
  };

  // ---- prologue: G(0..3), B(0), B(1)  (order defines the vmcnt ledger) ----
  issueG(0);
  issueG(1);
  issueG(2);
  issueG(3);
  issueB(0);
  issueB(1);
  __builtin_amdgcn_sched_barrier(0);

  // ---- main loop: counted vmcnt from the exact issue-position ledger ----
#pragma unroll
  for (int s = 0; s < KSTEPS; s++) {
    vwait(newerCnt(s, KSTEPS, NG));
    __builtin_amdgcn_s_barrier();
    __builtin_amdgcn_sched_barrier(0);
    if (s + 2 < KSTEPS) issueB(s + 2);
    if (s + 4 < KSTEPS) issueG(s + 4);
    __builtin_amdgcn_sched_barrier(0);
    computeS(s);
  }

  // ---- epilogue: C/D frag col=lane&15, row=(lane>>4)*4+reg ----
#pragma unroll
  for (int j = 0; j < 5; j++) {
    int c = wave * 80 + j * 16 + r;
    if (c >= HH) continue;
    float bia = (MODE == 2) ? bias[c] : 0.f;
#pragma unroll
    for (int i = 0; i < 4; i++) {
#pragma unroll
      for (int ri = 0; ri < 4; ri++) {
        int g = gm0 + i * 16 + q * 4 + ri;
        if (g >= M) continue;
        float v = acc[i][j][ri];
        if (MODE == 2) {
          hid_out[(size_t)g * HH + c] = fmaxf(v + bia, 0.f);
        } else {
          float rv = fmaxf(v, 0.f);
          if (g == 0) rv = 0.f;
          msg_out[(size_t)g * HH + c] = __float2bfloat16(rv);
        }
      }
    }
  }
}

// per-molecule mean over sorted mol_id (binary search, no atomics)
__global__ void readout_k(const float* __restrict__ hid, const int* __restrict__ mol_id,
                          float* __restrict__ out, int A)
{
  __shared__ int bnd[2];
  int m = blockIdx.x;
  if (threadIdx.x < 2) {
    int target = m + (int)threadIdx.x;
    int lo = 0, hi = A;
    while (lo < hi) { int mid = (lo + hi) >> 1; if (mol_id[mid] < target) lo = mid + 1; else hi = mid; }
    bnd[threadIdx.x] = lo;
  }
  __syncthreads();
  int s = bnd[0], e = bnd[1];
  int h = threadIdx.x;
  if (h >= HH) return;
  float acc = 0.f;
  for (int a = s; a < e; a++) acc += hid[(size_t)a * HH + h];
  int cnt = e - s; if (cnt < 1) cnt = 1;
  out[(size_t)m * HH + h] = acc / (float)cnt;
}

extern "C" void kernel_launch(void* const* d_in, const int* in_sizes, int n_in,
                              void* d_out, int out_size, void* d_ws, size_t ws_size,
                              hipStream_t stream)
{
  const float* f_atoms[2] = {(const float*)d_in[0], (const float*)d_in[2]};
  const float* f_bonds[2] = {(const float*)d_in[1], (const float*)d_in[3]};
  const float* W_i[2]     = {(const float*)d_in[4], (const float*)d_in[5]};
  const float* W_h[2]     = {(const float*)d_in[6], (const float*)d_in[7]};
  const float* W_o[2]     = {(const float*)d_in[8], (const float*)d_in[10]};
  const float* b_o[2]     = {(const float*)d_in[9], (const float*)d_in[11]};
  const int* a2b[2]    = {(const int*)d_in[12], (const int*)d_in[16]};
  const int* b2a[2]    = {(const int*)d_in[13], (const int*)d_in[17]};
  const int* b2revb[2] = {(const int*)d_in[14], (const int*)d_in[18]};
  const int* mol_id[2] = {(const int*)d_in[15], (const int*)d_in[19]};
  const int A = in_sizes[0] / AFD;   // 100001
  const int B = in_sizes[1] / BFD;   // 200001

  // ws: M0 | M1/hid | amsg | fbb | fab | 4x WT   (~397 MB; proven fits)
  auto al = [](size_t x){ return (x + 255) & ~(size_t)255; };
  size_t r0 = al((size_t)B * HH * sizeof(bf16));
  size_t r1sz = (size_t)B * HH * sizeof(bf16);
  size_t hsz  = (size_t)A * HH * sizeof(float);
  size_t r1 = al(r1sz > hsz ? r1sz : hsz);
  size_t amsz = al((size_t)A * HH * sizeof(bf16));
  size_t fbbsz = al((size_t)B * FBP * sizeof(bf16));
  size_t fabsz = al((size_t)A * FBP * sizeof(bf16));
  size_t wtsz = al((size_t)NWT * sizeof(bf16));
  if (ws_size < r0 + r1 + amsz + fbbsz + fabsz + 4 * wtsz) return;

  char* ws = (char*)d_ws;
  bf16*  M0  = (bf16*)ws;
  bf16*  M1  = (bf16*)(ws + r0);
  float* hid = (float*)(ws + r0);
  bf16*  amsg = (bf16*)(ws + r0 + r1);
  bf16*  fbb  = (bf16*)(ws + r0 + r1 + amsz);
  bf16*  fab  = (bf16*)(ws + r0 + r1 + amsz + fbbsz);
  size_t wofs = r0 + r1 + amsz + fbbsz + fabsz;
  bf16* WT1[2] = {(bf16*)(ws + wofs),            (bf16*)(ws + wofs + wtsz)};
  bf16* WT2[2] = {(bf16*)(ws + wofs + 2 * wtsz), (bf16*)(ws + wofs + 3 * wtsz)};

  dim3 blk(256);
  dim3 gW((NWT + 255) / 256);
  dim3 gB((B + 63) / 64);
  dim3 gA((A + 63) / 64);
  dim3 gG((A * 38 + 255) / 256);

  for (int p = 0; p < 2; p++) {
    build_wt<<<gW, blk, 0, stream>>>(W_i[p], W_h[p], BFD, WT1[p]);
    build_wt<<<gW, blk, 0, stream>>>(W_o[p], W_o[p] + (size_t)AFD * HH, AFD, WT2[p]);
  }

  for (int p = 0; p < 2; p++) {
    float* out_p = (float*)d_out + (size_t)p * NMOLS * HH;
    cvt_pad<<<(B * 20 + 255) / 256, blk, 0, stream>>>(f_bonds[p], BFD, fbb, B);
    cvt_pad<<<(A * 20 + 255) / 256, blk, 0, stream>>>(f_atoms[p], AFD, fab, A);
    // msg(M0) = relu(fbb @ W_i), row0=0
    gemm_g<0><<<gB, blk, 0, stream>>>(fbb, WT1[p], nullptr, nullptr,
                                      nullptr, nullptr, nullptr, M0, nullptr, B);
    // iter 1: amsg = gather6(M0); M1 = relu(fbb@Wi + amsg[b2a]@Wh - M0[b2revb]@Wh)
    gather6_k<<<gG, blk, 0, stream>>>(M0, a2b[p], amsg, A);
    gemm_g<1><<<gB, blk, 0, stream>>>(fbb, WT1[p], b2a[p], b2revb[p],
                                      amsg, M0, nullptr, M1, nullptr, B);
    // iter 2
    gather6_k<<<gG, blk, 0, stream>>>(M1, a2b[p], amsg, A);
    gemm_g<1><<<gB, blk, 0, stream>>>(fbb, WT1[p], b2a[p], b2revb[p],
                                      amsg, M1, nullptr, M0, nullptr, B);
    // output layer
    gather6_k<<<gG, blk, 0, stream>>>(M0, a2b[p], amsg, A);
    gemm_g<2><<<gA, blk, 0, stream>>>(fab, WT2[p], nullptr, nullptr,
                                      amsg, nullptr, b_o[p], nullptr, hid, A);
    // per-molecule mean readout
    readout_k<<<NMOLS, 320, 0, stream>>>(hid, mol_id[p], out_p, A);
  }
}

// Round 14
// 1758.295 us; speedup vs baseline: 1.1785x; 1.0169x over previous
//
#include <hip/hip_runtime.h>
#include <hip/hip_bf16.h>

typedef __hip_bfloat16 bf16;
typedef __attribute__((ext_vector_type(8))) short bf16x8;
typedef __attribute__((ext_vector_type(4))) float f32x4;
typedef __attribute__((ext_vector_type(4))) int i32x4;

#define HH 300     // hidden
#define NMOLS 2000
#define AFD 133    // atom feature dim
#define BFD 147    // bond feature dim
#define KP 480     // padded K of WT buffers (15 steps of 32)
#define GOFS 160   // tail region starts at k=160 (step 5)
#define NWT (320 * KP)
#define FBP 160    // padded bf16 feature row length

// ---- direct global->LDS: dest = wave-uniform base + lane*16 ----
__device__ inline void gll16(short* lds_base, const void* gsrc) {
  auto l = (__attribute__((address_space(3))) short*)lds_base;
  auto g = (const __attribute__((address_space(1))) char*)gsrc;
  __builtin_amdgcn_global_load_lds(g, l, 16, 0, 0);
}

// counted vmcnt; full case coverage 8..34; default = full drain (conservative:
// correctness never depends on constant folding)
__device__ __forceinline__ void vwait(int n) {
  switch (n) {
    case 8:  asm volatile("s_waitcnt vmcnt(8)"  ::: "memory"); break;
    case 9:  asm volatile("s_waitcnt vmcnt(9)"  ::: "memory"); break;
    case 10: asm volatile("s_waitcnt vmcnt(10)" ::: "memory"); break;
    case 11: asm volatile("s_waitcnt vmcnt(11)" ::: "memory"); break;
    case 12: asm volatile("s_waitcnt vmcnt(12)" ::: "memory"); break;
    case 13: asm volatile("s_waitcnt vmcnt(13)" ::: "memory"); break;
    case 14: asm volatile("s_waitcnt vmcnt(14)" ::: "memory"); break;
    case 15: asm volatile("s_waitcnt vmcnt(15)" ::: "memory"); break;
    case 16: asm volatile("s_waitcnt vmcnt(16)" ::: "memory"); break;
    case 17: asm volatile("s_waitcnt vmcnt(17)" ::: "memory"); break;
    case 18: asm volatile("s_waitcnt vmcnt(18)" ::: "memory"); break;
    case 19: asm volatile("s_waitcnt vmcnt(19)" ::: "memory"); break;
    case 20: asm volatile("s_waitcnt vmcnt(20)" ::: "memory"); break;
    case 21: asm volatile("s_waitcnt vmcnt(21)" ::: "memory"); break;
    case 22: asm volatile("s_waitcnt vmcnt(22)" ::: "memory"); break;
    case 23: asm volatile("s_waitcnt vmcnt(23)" ::: "memory"); break;
    case 24: asm volatile("s_waitcnt vmcnt(24)" ::: "memory"); break;
    case 25: asm volatile("s_waitcnt vmcnt(25)" ::: "memory"); break;
    case 26: asm volatile("s_waitcnt vmcnt(26)" ::: "memory"); break;
    case 27: asm volatile("s_waitcnt vmcnt(27)" ::: "memory"); break;
    case 28: asm volatile("s_waitcnt vmcnt(28)" ::: "memory"); break;
    case 29: asm volatile("s_waitcnt vmcnt(29)" ::: "memory"); break;
    case 30: asm volatile("s_waitcnt vmcnt(30)" ::: "memory"); break;
    case 31: asm volatile("s_waitcnt vmcnt(31)" ::: "memory"); break;
    case 32: asm volatile("s_waitcnt vmcnt(32)" ::: "memory"); break;
    case 33: asm volatile("s_waitcnt vmcnt(33)" ::: "memory"); break;
    case 34: asm volatile("s_waitcnt vmcnt(34)" ::: "memory"); break;
    default: asm volatile("s_waitcnt vmcnt(0)"  ::: "memory"); break;
  }
}

// Per-wave VMEM issue schedule (batches, in order):
//   prologue: G(0) G(1) G(2) G(3) B(0) B(1)
//   iter u:   [vwait][barrier] B(u+2) G(u+4) compute(u)
// B batch = 5 loads; G(t) batch = ng(t) glls (MODE1: 1 for t<5, 2 for t>=5).
// vmcnt retires in issue order: waiting "outstanding <= #ops issued after G(s)"
// guarantees G(s) landed.
__device__ __forceinline__ int newerCnt(int s, int K, int NGT) {
  int posGs = (s <= 3) ? s : 7 + 2 * (s - 4);
  int W = 6 + 2 * s;                    // wait point = start of iter s
  int n = 0;
  for (int t = 0; t < K; t++) {
    int pb = (t <= 1) ? (4 + t) : (6 + 2 * (t - 2));
    int pg = (t <= 3) ? t : (7 + 2 * (t - 4));
    if (pb > posGs && pb < W) n += 5;
    if (pg > posGs && pg < W) n += (t < 5 ? 1 : NGT);
  }
  return n;
}

// ---- build WT[c][k] bf16: k<fd -> W0[k][c]; 160<=k<460 -> W1[k-160][c]; else 0 ----
// Zero pads load-bearing: A-tail overruns rows; products hit WT==0.
__global__ void build_wt(const float* __restrict__ W0, const float* __restrict__ W1,
                         int fd, bf16* __restrict__ WT)
{
  int idx = blockIdx.x * 256 + threadIdx.x;
  if (idx >= NWT) return;
  int c = idx / KP, k = idx - c * KP;
  float v = 0.f;
  if (c < HH) {
    if (k < fd) v = W0[(size_t)k * HH + c];
    else if (k >= GOFS && k < GOFS + HH) v = W1[(size_t)(k - GOFS) * HH + c];
  }
  WT[idx] = __float2bfloat16(v);
}

// ---- pad/convert features: Y[r][0..159] = bf16(X[r][0..fd-1]) | zeros ----
__global__ __launch_bounds__(256)
void cvt_pad(const float* __restrict__ X, int fd, bf16* __restrict__ Y, int N)
{
  int idx = blockIdx.x * 256 + threadIdx.x;
  if (idx >= N * 20) return;
  int rr = idx / 20, c8 = (idx - rr * 20) * 8;
  short t[8];
#pragma unroll
  for (int j = 0; j < 8; j++) {
    int c = c8 + j;
    float v = (c < fd) ? X[(size_t)rr * fd + c] : 0.f;
    union { bf16 b; short s; } cv; cv.b = __float2bfloat16(v); t[j] = cv.s;
  }
  *(bf16x8*)(Y + (size_t)rr * FBP + c8) = *(const bf16x8*)t;
}

// ---- amsg[a][k] = sum_j msg[a2b[a][j]][k]; 8 elems/thread ----
__global__ __launch_bounds__(256)
void gather6_k(const bf16* __restrict__ msg, const int* __restrict__ a2b,
               bf16* __restrict__ amsg, int A)
{
  int idx = blockIdx.x * 256 + threadIdx.x;
  if (idx >= A * 38) return;
  int a = idx / 38;
  int k8 = (idx - a * 38) * 8;
  const int* p = a2b + (size_t)a * 6;
  uint2 u0[6], u1[6];
#pragma unroll
  for (int j = 0; j < 6; j++) {
    const bf16* q = msg + (size_t)p[j] * HH + k8;
    u0[j] = *(const uint2*)q;
    u1[j] = *(const uint2*)(q + 4);   // may cross row end; pad-safe, unused
  }
  float s[8] = {0.f,0.f,0.f,0.f,0.f,0.f,0.f,0.f};
#pragma unroll
  for (int j = 0; j < 6; j++) {
    unsigned w[4] = {u0[j].x, u0[j].y, u1[j].x, u1[j].y};
#pragma unroll
    for (int q2 = 0; q2 < 4; q2++) {
      union { unsigned u; float f; } lo, hi;
      lo.u = w[q2] << 16;
      hi.u = w[q2] & 0xffff0000u;
      s[2 * q2]     += lo.f;
      s[2 * q2 + 1] += hi.f;
    }
  }
  short t[8];
#pragma unroll
  for (int j = 0; j < 8; j++) {
    union { bf16 b; short sh; } cv; cv.b = __float2bfloat16(s[j]); t[j] = cv.sh;
  }
  bf16* dst = amsg + (size_t)a * HH + k8;
  *(uint2*)dst = *(const uint2*)t;
  if (k8 + 8 <= HH) *(uint2*)((short*)dst + 4) = *(const uint2*)(t + 4);
}

// ============ gll-staged MFMA GEMM: 64 rows x 320 cols, 4 waves split N ============
// r13 structure + variable-NG ledger (no duplicate FB gll) + setprio around MFMA
// + bf16 hid output.
// MODE 0: C = fbb@Wi (5 steps);                          msg = relu(C), row0=0
// MODE 1: C = fbb@Wi + amsg[b2a]@Wh + (-msg[b2revb])@Wh; msg = relu(C), row0=0
// MODE 2: C = [fab | amsg]@Wo;                           hid = bf16(relu(C + bias))
template<int MODE>
__global__ __launch_bounds__(256)
void gemm_g(const bf16* __restrict__ FB, const bf16* __restrict__ WT,
            const int* __restrict__ b2a, const int* __restrict__ b2revb,
            const bf16* __restrict__ amsg, const bf16* __restrict__ msgc,
            const float* __restrict__ bias,
            bf16* __restrict__ msg_out, bf16* __restrict__ hid_out, int M)
{
  constexpr int KSTEPS = (MODE == 0) ? 5 : 15;
  constexpr bool DUAL = (MODE == 1);
  constexpr int D = 5;
  constexpr int NGT = DUAL ? 2 : 1;   // glls per tail step

  __shared__ __align__(16) short As[D][2048];           // 64 rows x 32 k per slot
  __shared__ __align__(16) short Ms[DUAL ? D : 1][2048];

  const int tid = threadIdx.x;
  const int lane = tid & 63;
  const int wave = tid >> 6;
  const int gm0 = blockIdx.x * 64;

  // staging map: wave stages rows [wave*16, wave*16+16); LDS dest linear (gll),
  // swizzle applied on SOURCE k-chunk; read side applies same XOR.
  const int lrow = wave * 16 + (lane >> 2);
  const int ssl = (lane & 3) ^ ((lrow >> 1) & 3);
  const int grow = min(gm0 + lrow, M - 1);   // clamped (stores guarded)
  int ba = 0, rb = 0;
  if constexpr (DUAL) { ba = b2a[grow]; rb = b2revb[grow]; }

  // compute map
  const int r = lane & 15, q = lane >> 4;
  int aoff[4];
#pragma unroll
  for (int i = 0; i < 4; i++) {
    int rr = i * 16 + r;
    aoff[i] = rr * 32 + ((q ^ (rr >> 1)) & 3) * 8;
  }
  const bf16* bb = WT + (size_t)(wave * 80 + r) * KP + q * 8;

  f32x4 acc[4][5];
#pragma unroll
  for (int i = 0; i < 4; i++)
#pragma unroll
    for (int j = 0; j < 5; j++) acc[i][j] = (f32x4){0.f, 0.f, 0.f, 0.f};

  bf16x8 bufB[3][5];                 // ring of 3, distance-2 prefetch
  auto issueB = [&](int s) {
#pragma unroll
    for (int j = 0; j < 5; j++)
      bufB[s % 3][j] = *(const bf16x8*)(bb + (size_t)j * 16 * KP + s * 32);
  };

  auto issueG = [&](int s) {
    short* la = &As[s % D][wave * 512];
    if constexpr (MODE == 0) {
      gll16(la, FB + (size_t)grow * FBP + s * 32 + ssl * 8);
    } else if constexpr (MODE == 2) {
      if (s < 5) gll16(la, FB + (size_t)grow * FBP + s * 32 + ssl * 8);
      else       gll16(la, amsg + (size_t)grow * HH + (s - 5) * 32 + ssl * 8);
    } else {
      if (s < 5) {
        gll16(la, FB + (size_t)grow * FBP + s * 32 + ssl * 8);  // 1 gll (ng=1)
      } else {
        short* lm = &Ms[s % D][wave * 512];
        int kk = (s - 5) * 32 + ssl * 8;
        gll16(la, amsg + (size_t)ba * HH + kk);
        gll16(lm, msgc + (size_t)rb * HH + kk);                 // 2 glls (ng=2)
      }
    }
  };

  auto computeS = [&](int s) {
    const short* ca = &As[s % D][0];
    bf16x8 af[4];
#pragma unroll
    for (int i = 0; i < 4; i++) af[i] = *(const bf16x8*)(ca + aoff[i]);
    bf16x8 mfn[4];
    if constexpr (DUAL) {
      if (s >= 5) {
        const short* cm = &Ms[s % D][0];
#pragma unroll
        for (int i = 0; i < 4; i++) {
          union { bf16x8 h; i32x4 w; } u;
          u.h = *(const bf16x8*)(cm + aoff[i]);
          u.w = u.w ^ (int)0x80008000;    // bf16 sign-flip: (-msg)@Wh
          mfn[i] = u.h;
        }
      }
    }
    __builtin_amdgcn_s_setprio(1);
#pragma unroll
    for (int j = 0; j < 5; j++)
#pragma unroll
      for (int i = 0; i < 4; i++) {
        acc[i][j] = __builtin_amdgcn_mfma_f32_16x16x32_bf16(af[i], bufB[s % 3][j], acc[i][j], 0, 0, 0);
        if constexpr (DUAL) {
          if (s >= 5)
            acc[i][j] = __builtin_amdgcn_mfma_f32_16x16x32_bf16(mfn[i], bufB[s % 3][j], acc[i][j], 0, 0, 0);
        }
      }
    __builtin_amdgcn_s_setprio(0);
  };

  // ---- prologue: G(0..3), B(0), B(1)  (order defines the vmcnt ledger) ----
  issueG(0);
  issueG(1);
  issueG(2);
  issueG(3);
  issueB(0);
  issueB(1);
  __builtin_amdgcn_sched_barrier(0);

  // ---- main loop: counted vmcnt from the exact issue-position ledger ----
#pragma unroll
  for (int s = 0; s < KSTEPS; s++) {
    vwait(newerCnt(s, KSTEPS, NGT));
    __builtin_amdgcn_s_barrier();
    __builtin_amdgcn_sched_barrier(0);
    if (s + 2 < KSTEPS) issueB(s + 2);
    if (s + 4 < KSTEPS) issueG(s + 4);
    __builtin_amdgcn_sched_barrier(0);
    computeS(s);
  }

  // ---- epilogue: C/D frag col=lane&15, row=(lane>>4)*4+reg ----
#pragma unroll
  for (int j = 0; j < 5; j++) {
    int c = wave * 80 + j * 16 + r;
    if (c >= HH) continue;
    float bia = (MODE == 2) ? bias[c] : 0.f;
#pragma unroll
    for (int i = 0; i < 4; i++) {
#pragma unroll
      for (int ri = 0; ri < 4; ri++) {
        int g = gm0 + i * 16 + q * 4 + ri;
        if (g >= M) continue;
        float v = acc[i][j][ri];
        if (MODE == 2) {
          hid_out[(size_t)g * HH + c] = __float2bfloat16(fmaxf(v + bia, 0.f));
        } else {
          float rv = fmaxf(v, 0.f);
          if (g == 0) rv = 0.f;
          msg_out[(size_t)g * HH + c] = __float2bfloat16(rv);
        }
      }
    }
  }
}

// per-molecule mean over sorted mol_id (binary search, no atomics); hid is bf16
__global__ void readout_k(const bf16* __restrict__ hid, const int* __restrict__ mol_id,
                          float* __restrict__ out, int A)
{
  __shared__ int bnd[2];
  int m = blockIdx.x;
  if (threadIdx.x < 2) {
    int target = m + (int)threadIdx.x;
    int lo = 0, hi = A;
    while (lo < hi) { int mid = (lo + hi) >> 1; if (mol_id[mid] < target) lo = mid + 1; else hi = mid; }
    bnd[threadIdx.x] = lo;
  }
  __syncthreads();
  int s = bnd[0], e = bnd[1];
  int h = threadIdx.x;
  if (h >= HH) return;
  float acc = 0.f;
  for (int a = s; a < e; a++) acc += __bfloat162float(hid[(size_t)a * HH + h]);
  int cnt = e - s; if (cnt < 1) cnt = 1;
  out[(size_t)m * HH + h] = acc / (float)cnt;
}

extern "C" void kernel_launch(void* const* d_in, const int* in_sizes, int n_in,
                              void* d_out, int out_size, void* d_ws, size_t ws_size,
                              hipStream_t stream)
{
  const float* f_atoms[2] = {(const float*)d_in[0], (const float*)d_in[2]};
  const float* f_bonds[2] = {(const float*)d_in[1], (const float*)d_in[3]};
  const float* W_i[2]     = {(const float*)d_in[4], (const float*)d_in[5]};
  const float* W_h[2]     = {(const float*)d_in[6], (const float*)d_in[7]};
  const float* W_o[2]     = {(const float*)d_in[8], (const float*)d_in[10]};
  const float* b_o[2]     = {(const float*)d_in[9], (const float*)d_in[11]};
  const int* a2b[2]    = {(const int*)d_in[12], (const int*)d_in[16]};
  const int* b2a[2]    = {(const int*)d_in[13], (const int*)d_in[17]};
  const int* b2revb[2] = {(const int*)d_in[14], (const int*)d_in[18]};
  const int* mol_id[2] = {(const int*)d_in[15], (const int*)d_in[19]};
  const int A = in_sizes[0] / AFD;   // 100001
  const int B = in_sizes[1] / BFD;   // 200001

  // ws: M0 | M1 (hid bf16 overlays) | amsg | fbb | fab | 4x WT  (~397 MB; proven)
  auto al = [](size_t x){ return (x + 255) & ~(size_t)255; };
  size_t r0 = al((size_t)B * HH * sizeof(bf16));
  size_t r1 = al((size_t)B * HH * sizeof(bf16));
  size_t amsz = al((size_t)A * HH * sizeof(bf16));
  size_t fbbsz = al((size_t)B * FBP * sizeof(bf16));
  size_t fabsz = al((size_t)A * FBP * sizeof(bf16));
  size_t wtsz = al((size_t)NWT * sizeof(bf16));
  if (ws_size < r0 + r1 + amsz + fbbsz + fabsz + 4 * wtsz) return;

  char* ws = (char*)d_ws;
  bf16*  M0  = (bf16*)ws;
  bf16*  M1  = (bf16*)(ws + r0);
  bf16*  hid = (bf16*)(ws + r0);            // overlays M1 region (bf16, A*300)
  bf16*  amsg = (bf16*)(ws + r0 + r1);
  bf16*  fbb  = (bf16*)(ws + r0 + r1 + amsz);
  bf16*  fab  = (bf16*)(ws + r0 + r1 + amsz + fbbsz);
  size_t wofs = r0 + r1 + amsz + fbbsz + fabsz;
  bf16* WT1[2] = {(bf16*)(ws + wofs),            (bf16*)(ws + wofs + wtsz)};
  bf16* WT2[2] = {(bf16*)(ws + wofs + 2 * wtsz), (bf16*)(ws + wofs + 3 * wtsz)};

  dim3 blk(256);
  dim3 gW((NWT + 255) / 256);
  dim3 gB((B + 63) / 64);
  dim3 gA((A + 63) / 64);
  dim3 gG((A * 38 + 255) / 256);

  for (int p = 0; p < 2; p++) {
    build_wt<<<gW, blk, 0, stream>>>(W_i[p], W_h[p], BFD, WT1[p]);
    build_wt<<<gW, blk, 0, stream>>>(W_o[p], W_o[p] + (size_t)AFD * HH, AFD, WT2[p]);
  }

  for (int p = 0; p < 2; p++) {
    float* out_p = (float*)d_out + (size_t)p * NMOLS * HH;
    cvt_pad<<<(B * 20 + 255) / 256, blk, 0, stream>>>(f_bonds[p], BFD, fbb, B);
    cvt_pad<<<(A * 20 + 255) / 256, blk, 0, stream>>>(f_atoms[p], AFD, fab, A);
    // msg(M0) = relu(fbb @ W_i), row0=0
    gemm_g<0><<<gB, blk, 0, stream>>>(fbb, WT1[p], nullptr, nullptr,
                                      nullptr, nullptr, nullptr, M0, nullptr, B);
    // iter 1: amsg = gather6(M0); M1 = relu(fbb@Wi + amsg[b2a]@Wh - M0[b2revb]@Wh)
    gather6_k<<<gG, blk, 0, stream>>>(M0, a2b[p], amsg, A);
    gemm_g<1><<<gB, blk, 0, stream>>>(fbb, WT1[p], b2a[p], b2revb[p],
                                      amsg, M0, nullptr, M1, nullptr, B);
    // iter 2
    gather6_k<<<gG, blk, 0, stream>>>(M1, a2b[p], amsg, A);
    gemm_g<1><<<gB, blk, 0, stream>>>(fbb, WT1[p], b2a[p], b2revb[p],
                                      amsg, M1, nullptr, M0, nullptr, B);
    // output layer: hid(bf16) = relu([fab | gather6(M0)]@Wo + b)  (overlays M1)
    gather6_k<<<gG, blk, 0, stream>>>(M0, a2b[p], amsg, A);
    gemm_g<2><<<gA, blk, 0, stream>>>(fab, WT2[p], nullptr, nullptr,
                                      amsg, nullptr, b_o[p], nullptr, hid, A);
    // per-molecule mean readout
    readout_k<<<NMOLS, 320, 0, stream>>>(hid, mol_id[p], out_p, A);
  }
}

// Round 15
// 1647.245 us; speedup vs baseline: 1.2579x; 1.0674x over previous
//
#include <hip/hip_runtime.h>
#include <hip/hip_bf16.h>

typedef __hip_bfloat16 bf16;
typedef __attribute__((ext_vector_type(8))) short bf16x8;
typedef __attribute__((ext_vector_type(4))) float f32x4;
typedef __attribute__((ext_vector_type(4))) int i32x4;

#define HH 300     // hidden
#define NMOLS 2000
#define AFD 133    // atom feature dim
#define BFD 147    // bond feature dim
#define KP 480     // padded K of WT buffers (15 steps of 32)
#define GOFS 160   // tail region starts at k=160 (step 5)
#define NWT (320 * KP)
#define FBP 160    // padded bf16 feature row length

// ---- direct global->LDS: dest = wave-uniform base + lane*16 ----
__device__ inline void gll16(short* lds_base, const void* gsrc) {
  auto l = (__attribute__((address_space(3))) short*)lds_base;
  auto g = (const __attribute__((address_space(1))) char*)gsrc;
  __builtin_amdgcn_global_load_lds(g, l, 16, 0, 0);
}

// counted vmcnt; cases cover {5,10,20,25}; default = full drain (conservative:
// correctness never depends on constant folding)
__device__ __forceinline__ void vwait(int n) {
  switch (n) {
    case 5:  asm volatile("s_waitcnt vmcnt(5)"  ::: "memory"); break;
    case 10: asm volatile("s_waitcnt vmcnt(10)" ::: "memory"); break;
    case 20: asm volatile("s_waitcnt vmcnt(20)" ::: "memory"); break;
    case 25: asm volatile("s_waitcnt vmcnt(25)" ::: "memory"); break;
    default: asm volatile("s_waitcnt vmcnt(0)"  ::: "memory"); break;
  }
}

// ---- build WT[c][k] bf16: k<fd -> W0[k][c]; 160<=k<460 -> W1[k-160][c]; else 0 ----
// Zero pads load-bearing: A-tail overruns rows; products hit WT==0.
__global__ void build_wt(const float* __restrict__ W0, const float* __restrict__ W1,
                         int fd, bf16* __restrict__ WT)
{
  int idx = blockIdx.x * 256 + threadIdx.x;
  if (idx >= NWT) return;
  int c = idx / KP, k = idx - c * KP;
  float v = 0.f;
  if (c < HH) {
    if (k < fd) v = W0[(size_t)k * HH + c];
    else if (k >= GOFS && k < GOFS + HH) v = W1[(size_t)(k - GOFS) * HH + c];
  }
  WT[idx] = __float2bfloat16(v);
}

// ---- pad/convert features: Y[r][0..159] = bf16(X[r][0..fd-1]) | zeros ----
__global__ __launch_bounds__(256)
void cvt_pad(const float* __restrict__ X, int fd, bf16* __restrict__ Y, int N)
{
  int idx = blockIdx.x * 256 + threadIdx.x;
  if (idx >= N * 20) return;
  int rr = idx / 20, c8 = (idx - rr * 20) * 8;
  short t[8];
#pragma unroll
  for (int j = 0; j < 8; j++) {
    int c = c8 + j;
    float v = (c < fd) ? X[(size_t)rr * fd + c] : 0.f;
    union { bf16 b; short s; } cv; cv.b = __float2bfloat16(v); t[j] = cv.s;
  }
  *(bf16x8*)(Y + (size_t)rr * FBP + c8) = *(const bf16x8*)t;
}

// ---- amsg[a][k] = sum_j msg[a2b[a][j]][k]; 8 elems/thread ----
__global__ __launch_bounds__(256)
void gather6_k(const bf16* __restrict__ msg, const int* __restrict__ a2b,
               bf16* __restrict__ amsg, int A)
{
  int idx = blockIdx.x * 256 + threadIdx.x;
  if (idx >= A * 38) return;
  int a = idx / 38;
  int k8 = (idx - a * 38) * 8;
  const int* p = a2b + (size_t)a * 6;
  uint2 u0[6], u1[6];
#pragma unroll
  for (int j = 0; j < 6; j++) {
    const bf16* q = msg + (size_t)p[j] * HH + k8;
    u0[j] = *(const uint2*)q;
    u1[j] = *(const uint2*)(q + 4);   // may cross row end; pad-safe, unused
  }
  float s[8] = {0.f,0.f,0.f,0.f,0.f,0.f,0.f,0.f};
#pragma unroll
  for (int j = 0; j < 6; j++) {
    unsigned w[4] = {u0[j].x, u0[j].y, u1[j].x, u1[j].y};
#pragma unroll
    for (int q2 = 0; q2 < 4; q2++) {
      union { unsigned u; float f; } lo, hi;
      lo.u = w[q2] << 16;
      hi.u = w[q2] & 0xffff0000u;
      s[2 * q2]     += lo.f;
      s[2 * q2 + 1] += hi.f;
    }
  }
  short t[8];
#pragma unroll
  for (int j = 0; j < 8; j++) {
    union { bf16 b; short sh; } cv; cv.b = __float2bfloat16(s[j]); t[j] = cv.sh;
  }
  bf16* dst = amsg + (size_t)a * HH + k8;
  *(uint2*)dst = *(const uint2*)t;
  if (k8 + 8 <= HH) *(uint2*)((short*)dst + 4) = *(const uint2*)(t + 4);
}

// ============ slab-fetch gll MFMA GEMM: 64 rows x 320 cols, 4 waves split N ============
// K = 3 slabs x 5 steps (MODE0: 1 slab). Per slab each wave issues its row as
// 5 ADJACENT glls (320B contiguous burst per random row). One barrier per slab.
// Issue order: B-batches BEFORE gll slabs -> compiler B-waits never force-retire
// younger glls (vmcnt retires in order).
// MODE 0: C = fbb@Wi (5 steps);                          msg = relu(C), row0=0
// MODE 1: C = fbb@Wi + amsg[b2a]@Wh + (-msg[b2revb])@Wh; msg = relu(C), row0=0
// MODE 2: C = [fab | amsg]@Wo;                           hid = bf16(relu(C + bias))
template<int MODE>
__global__ __launch_bounds__(256)
void gemm_g(const bf16* __restrict__ FB, const bf16* __restrict__ WT,
            const int* __restrict__ b2a, const int* __restrict__ b2revb,
            const bf16* __restrict__ amsg, const bf16* __restrict__ msgc,
            const float* __restrict__ bias,
            bf16* __restrict__ msg_out, bf16* __restrict__ hid_out, int M)
{
  constexpr int KSTEPS = (MODE == 0) ? 5 : 15;
  constexpr bool DUAL = (MODE == 1);
  constexpr int NSLAB = (MODE == 0) ? 1 : 2;          // slab ring depth
  // vmcnt ledger (see schedule below):
  //   slab0 wait: newer than Gs0 = Gs1 glls        -> MODE1:10  MODE2:5  MODE0:0
  //   slab1 wait: newer than Gs1 = B2..B6          -> 25
  //   slab2 wait: newer than Gs2 = B8..B11         -> 20
  constexpr int W0C = (MODE == 1) ? 10 : (MODE == 2) ? 5 : 0;

  __shared__ __align__(16) short As[NSLAB * 5 * 2048];          // per step-slot 4KB
  __shared__ __align__(16) short Ms[DUAL ? NSLAB * 5 * 2048 : 16];

  const int tid = threadIdx.x;
  const int lane = tid & 63;
  const int wave = tid >> 6;
  const int gm0 = blockIdx.x * 64;

  // staging map: wave stages rows [wave*16, wave*16+16); LDS dest linear (gll),
  // swizzle applied on SOURCE k-chunk; read side applies same XOR.
  const int lrow = wave * 16 + (lane >> 2);
  const int ssl = (lane & 3) ^ ((lrow >> 1) & 3);
  const int grow = min(gm0 + lrow, M - 1);   // clamped (stores guarded)
  int ba = 0, rb = 0;
  if constexpr (DUAL) { ba = b2a[grow]; rb = b2revb[grow]; }

  // compute map
  const int r = lane & 15, q = lane >> 4;
  int aoff[4];
#pragma unroll
  for (int i = 0; i < 4; i++) {
    int rr = i * 16 + r;
    aoff[i] = rr * 32 + ((q ^ (rr >> 1)) & 3) * 8;
  }
  const bf16* bb = WT + (size_t)(wave * 80 + r) * KP + q * 8;

  f32x4 acc[4][5];
#pragma unroll
  for (int i = 0; i < 4; i++)
#pragma unroll
    for (int j = 0; j < 5; j++) acc[i][j] = (f32x4){0.f, 0.f, 0.f, 0.f};

  bf16x8 bufB[3][5];                 // ring of 3, distance-2 prefetch
  auto issueB = [&](int s) {
#pragma unroll
    for (int j = 0; j < 5; j++)
      bufB[s % 3][j] = *(const bf16x8*)(bb + (size_t)j * 16 * KP + s * 32);
  };

  // slab fetch: 5 adjacent 64B chunks of this wave's row(s) = 320B burst/row
  auto issueSlab = [&](int slab) {
    const int buf = slab % NSLAB;
    short* la = &As[buf * 5 * 2048 + wave * 512];
    if (slab == 0) {                 // head: feature row (exactly FBP*2 = 320B)
#pragma unroll
      for (int c = 0; c < 5; c++)
        gll16(la + c * 2048, FB + (size_t)grow * FBP + c * 32 + ssl * 8);
    } else {
      const int k0 = (slab - 1) * 160;   // tail k offset: slab1->0, slab2->160
      if constexpr (DUAL) {
#pragma unroll
        for (int c = 0; c < 5; c++)
          gll16(la + c * 2048, amsg + (size_t)ba * HH + k0 + c * 32 + ssl * 8);
        short* lm = &Ms[buf * 5 * 2048 + wave * 512];
#pragma unroll
        for (int c = 0; c < 5; c++)
          gll16(lm + c * 2048, msgc + (size_t)rb * HH + k0 + c * 32 + ssl * 8);
      } else {  // MODE 2
#pragma unroll
        for (int c = 0; c < 5; c++)
          gll16(la + c * 2048, amsg + (size_t)grow * HH + k0 + c * 32 + ssl * 8);
      }
    }
  };

  auto computeS = [&](int s) {
    const int buf = (s / 5) % NSLAB, c = s % 5;
    const short* ca = &As[(buf * 5 + c) * 2048];
    bf16x8 af[4];
#pragma unroll
    for (int i = 0; i < 4; i++) af[i] = *(const bf16x8*)(ca + aoff[i]);
    bf16x8 mfn[4];
    if constexpr (DUAL) {
      if (s >= 5) {
        const short* cm = &Ms[(buf * 5 + c) * 2048];
#pragma unroll
        for (int i = 0; i < 4; i++) {
          union { bf16x8 h; i32x4 w; } u;
          u.h = *(const bf16x8*)(cm + aoff[i]);
          u.w = u.w ^ (int)0x80008000;    // bf16 sign-flip: (-msg)@Wh
          mfn[i] = u.h;
        }
      }
    }
    __builtin_amdgcn_s_setprio(1);
#pragma unroll
    for (int j = 0; j < 5; j++)
#pragma unroll
      for (int i = 0; i < 4; i++) {
        acc[i][j] = __builtin_amdgcn_mfma_f32_16x16x32_bf16(af[i], bufB[s % 3][j], acc[i][j], 0, 0, 0);
        if constexpr (DUAL) {
          if (s >= 5)
            acc[i][j] = __builtin_amdgcn_mfma_f32_16x16x32_bf16(mfn[i], bufB[s % 3][j], acc[i][j], 0, 0, 0);
        }
      }
    __builtin_amdgcn_s_setprio(0);
  };

  // ---- prologue: B0, B1, Gs0, Gs1  (B BEFORE G: B-waits never retire glls) ----
  issueB(0);
  issueB(1);
  issueSlab(0);
  if (KSTEPS > 5) issueSlab(1);
  __builtin_amdgcn_sched_barrier(0);

  // ---- main loop: one vwait+barrier per slab; Gs2 issued after barrier@5 ----
#pragma unroll
  for (int s = 0; s < KSTEPS; s++) {
    if (s % 5 == 0) {
      __builtin_amdgcn_sched_barrier(0);   // pin: no B-issue sinks below the wait
      vwait(s == 0 ? W0C : (s == 5 ? 25 : 20));
      __builtin_amdgcn_s_barrier();
      __builtin_amdgcn_sched_barrier(0);
    }
    if (s + 2 < KSTEPS) issueB(s + 2);
    if (s == 5) {                          // issue slab2 (consumed at s=10)
      __builtin_amdgcn_sched_barrier(0);   // pin: B7 before Gs2
      issueSlab(2);
      __builtin_amdgcn_sched_barrier(0);   // pin: B8.. after Gs2
    }
    computeS(s);
  }

  // ---- epilogue: C/D frag col=lane&15, row=(lane>>4)*4+reg ----
#pragma unroll
  for (int j = 0; j < 5; j++) {
    int c = wave * 80 + j * 16 + r;
    if (c >= HH) continue;
    float bia = (MODE == 2) ? bias[c] : 0.f;
#pragma unroll
    for (int i = 0; i < 4; i++) {
#pragma unroll
      for (int ri = 0; ri < 4; ri++) {
        int g = gm0 + i * 16 + q * 4 + ri;
        if (g >= M) continue;
        float v = acc[i][j][ri];
        if (MODE == 2) {
          hid_out[(size_t)g * HH + c] = __float2bfloat16(fmaxf(v + bia, 0.f));
        } else {
          float rv = fmaxf(v, 0.f);
          if (g == 0) rv = 0.f;
          msg_out[(size_t)g * HH + c] = __float2bfloat16(rv);
        }
      }
    }
  }
}

// per-molecule mean over sorted mol_id (binary search, no atomics); hid is bf16
__global__ void readout_k(const bf16* __restrict__ hid, const int* __restrict__ mol_id,
                          float* __restrict__ out, int A)
{
  __shared__ int bnd[2];
  int m = blockIdx.x;
  if (threadIdx.x < 2) {
    int target = m + (int)threadIdx.x;
    int lo = 0, hi = A;
    while (lo < hi) { int mid = (lo + hi) >> 1; if (mol_id[mid] < target) lo = mid + 1; else hi = mid; }
    bnd[threadIdx.x] = lo;
  }
  __syncthreads();
  int s = bnd[0], e = bnd[1];
  int h = threadIdx.x;
  if (h >= HH) return;
  float acc = 0.f;
  for (int a = s; a < e; a++) acc += __bfloat162float(hid[(size_t)a * HH + h]);
  int cnt = e - s; if (cnt < 1) cnt = 1;
  out[(size_t)m * HH + h] = acc / (float)cnt;
}

extern "C" void kernel_launch(void* const* d_in, const int* in_sizes, int n_in,
                              void* d_out, int out_size, void* d_ws, size_t ws_size,
                              hipStream_t stream)
{
  const float* f_atoms[2] = {(const float*)d_in[0], (const float*)d_in[2]};
  const float* f_bonds[2] = {(const float*)d_in[1], (const float*)d_in[3]};
  const float* W_i[2]     = {(const float*)d_in[4], (const float*)d_in[5]};
  const float* W_h[2]     = {(const float*)d_in[6], (const float*)d_in[7]};
  const float* W_o[2]     = {(const float*)d_in[8], (const float*)d_in[10]};
  const float* b_o[2]     = {(const float*)d_in[9], (const float*)d_in[11]};
  const int* a2b[2]    = {(const int*)d_in[12], (const int*)d_in[16]};
  const int* b2a[2]    = {(const int*)d_in[13], (const int*)d_in[17]};
  const int* b2revb[2] = {(const int*)d_in[14], (const int*)d_in[18]};
  const int* mol_id[2] = {(const int*)d_in[15], (const int*)d_in[19]};
  const int A = in_sizes[0] / AFD;   // 100001
  const int B = in_sizes[1] / BFD;   // 200001

  // ws: M0 | M1 (hid bf16 overlays) | amsg | fbb | fab | 4x WT  (~397 MB; proven)
  auto al = [](size_t x){ return (x + 255) & ~(size_t)255; };
  size_t r0 = al((size_t)B * HH * sizeof(bf16));
  size_t r1 = al((size_t)B * HH * sizeof(bf16));
  size_t amsz = al((size_t)A * HH * sizeof(bf16));
  size_t fbbsz = al((size_t)B * FBP * sizeof(bf16));
  size_t fabsz = al((size_t)A * FBP * sizeof(bf16));
  size_t wtsz = al((size_t)NWT * sizeof(bf16));
  if (ws_size < r0 + r1 + amsz + fbbsz + fabsz + 4 * wtsz) return;

  char* ws = (char*)d_ws;
  bf16*  M0  = (bf16*)ws;
  bf16*  M1  = (bf16*)(ws + r0);
  bf16*  hid = (bf16*)(ws + r0);            // overlays M1 region (bf16, A*300)
  bf16*  amsg = (bf16*)(ws + r0 + r1);
  bf16*  fbb  = (bf16*)(ws + r0 + r1 + amsz);
  bf16*  fab  = (bf16*)(ws + r0 + r1 + amsz + fbbsz);
  size_t wofs = r0 + r1 + amsz + fbbsz + fabsz;
  bf16* WT1[2] = {(bf16*)(ws + wofs),            (bf16*)(ws + wofs + wtsz)};
  bf16* WT2[2] = {(bf16*)(ws + wofs + 2 * wtsz), (bf16*)(ws + wofs + 3 * wtsz)};

  dim3 blk(256);
  dim3 gW((NWT + 255) / 256);
  dim3 gB((B + 63) / 64);
  dim3 gA((A + 63) / 64);
  dim3 gG((A * 38 + 255) / 256);

  for (int p = 0; p < 2; p++) {
    build_wt<<<gW, blk, 0, stream>>>(W_i[p], W_h[p], BFD, WT1[p]);
    build_wt<<<gW, blk, 0, stream>>>(W_o[p], W_o[p] + (size_t)AFD * HH, AFD, WT2[p]);
  }

  for (int p = 0; p < 2; p++) {
    float* out_p = (float*)d_out + (size_t)p * NMOLS * HH;
    cvt_pad<<<(B * 20 + 255) / 256, blk, 0, stream>>>(f_bonds[p], BFD, fbb, B);
    cvt_pad<<<(A * 20 + 255) / 256, blk, 0, stream>>>(f_atoms[p], AFD, fab, A);
    // msg(M0) = relu(fbb @ W_i), row0=0
    gemm_g<0><<<gB, blk, 0, stream>>>(fbb, WT1[p], nullptr, nullptr,
                                      nullptr, nullptr, nullptr, M0, nullptr, B);
    // iter 1: amsg = gather6(M0); M1 = relu(fbb@Wi + amsg[b2a]@Wh - M0[b2revb]@Wh)
    gather6_k<<<gG, blk, 0, stream>>>(M0, a2b[p], amsg, A);
    gemm_g<1><<<gB, blk, 0, stream>>>(fbb, WT1[p], b2a[p], b2revb[p],
                                      amsg, M0, nullptr, M1, nullptr, B);
    // iter 2
    gather6_k<<<gG, blk, 0, stream>>>(M1, a2b[p], amsg, A);
    gemm_g<1><<<gB, blk, 0, stream>>>(fbb, WT1[p], b2a[p], b2revb[p],
                                      amsg, M1, nullptr, M0, nullptr, B);
    // output layer: hid(bf16) = relu([fab | gather6(M0)]@Wo + b)  (overlays M1)
    gather6_k<<<gG, blk, 0, stream>>>(M0, a2b[p], amsg, A);
    gemm_g<2><<<gA, blk, 0, stream>>>(fab, WT2[p], nullptr, nullptr,
                                      amsg, nullptr, b_o[p], nullptr, hid, A);
    // per-molecule mean readout
    readout_k<<<NMOLS, 320, 0, stream>>>(hid, mol_id[p], out_p, A);
  }
}

// Round 16
// 1582.670 us; speedup vs baseline: 1.3093x; 1.0408x over previous
//
#include <hip/hip_runtime.h>
#include <hip/hip_bf16.h>

typedef __hip_bfloat16 bf16;
typedef __attribute__((ext_vector_type(8))) short bf16x8;
typedef __attribute__((ext_vector_type(4))) float f32x4;
typedef __attribute__((ext_vector_type(4))) int i32x4;

#define HH 300     // hidden (logical)
#define HP 320     // padded row length of msg/amsg buffers (640B = 10 lines)
#define NMOLS 2000
#define AFD 133    // atom feature dim
#define BFD 147    // bond feature dim
#define KP 480     // padded K of WT buffers (15 steps of 32)
#define GOFS 160   // tail region starts at k=160 (step 5)
#define NWT (320 * KP)
#define FBP 160    // padded bf16 feature row length

// ---- direct global->LDS: dest = wave-uniform base + lane*16 ----
__device__ inline void gll16(short* lds_base, const void* gsrc) {
  auto l = (__attribute__((address_space(3))) short*)lds_base;
  auto g = (const __attribute__((address_space(1))) char*)gsrc;
  __builtin_amdgcn_global_load_lds(g, l, 16, 0, 0);
}

// counted vmcnt; cases cover {5,10,20,25}; default = full drain (conservative:
// correctness never depends on constant folding)
__device__ __forceinline__ void vwait(int n) {
  switch (n) {
    case 5:  asm volatile("s_waitcnt vmcnt(5)"  ::: "memory"); break;
    case 10: asm volatile("s_waitcnt vmcnt(10)" ::: "memory"); break;
    case 20: asm volatile("s_waitcnt vmcnt(20)" ::: "memory"); break;
    case 25: asm volatile("s_waitcnt vmcnt(25)" ::: "memory"); break;
    default: asm volatile("s_waitcnt vmcnt(0)"  ::: "memory"); break;
  }
}

// ---- build WT[c][k] bf16: k<fd -> W0[k][c]; 160<=k<460 -> W1[k-160][c]; else 0 ----
// Zero pads load-bearing: A-tail reads cols 300..319 (buffer pad, zeroed) against
// WT rows k>=460 (zero), and feature pad k in [fd,160) (zero).
__global__ void build_wt(const float* __restrict__ W0, const float* __restrict__ W1,
                         int fd, bf16* __restrict__ WT)
{
  int idx = blockIdx.x * 256 + threadIdx.x;
  if (idx >= NWT) return;
  int c = idx / KP, k = idx - c * KP;
  float v = 0.f;
  if (c < HH) {
    if (k < fd) v = W0[(size_t)k * HH + c];
    else if (k >= GOFS && k < GOFS + HH) v = W1[(size_t)(k - GOFS) * HH + c];
  }
  WT[idx] = __float2bfloat16(v);
}

// ---- pad/convert features: Y[r][0..159] = bf16(X[r][0..fd-1]) | zeros ----
__global__ __launch_bounds__(256)
void cvt_pad(const float* __restrict__ X, int fd, bf16* __restrict__ Y, int N)
{
  int idx = blockIdx.x * 256 + threadIdx.x;
  if (idx >= N * 20) return;
  int rr = idx / 20, c8 = (idx - rr * 20) * 8;
  short t[8];
#pragma unroll
  for (int j = 0; j < 8; j++) {
    int c = c8 + j;
    float v = (c < fd) ? X[(size_t)rr * fd + c] : 0.f;
    union { bf16 b; short s; } cv; cv.b = __float2bfloat16(v); t[j] = cv.s;
  }
  *(bf16x8*)(Y + (size_t)rr * FBP + c8) = *(const bf16x8*)t;
}

// ---- amsg[a][k] = sum_j msg[a2b[a][j]][k]; 8 elems/thread, 16B-aligned uint4 ----
// 40 threads/row cover the full 320-elem padded row; cols >=300 written as zero.
__global__ __launch_bounds__(256)
void gather6_k(const bf16* __restrict__ msg, const int* __restrict__ a2b,
               bf16* __restrict__ amsg, int A)
{
  int idx = blockIdx.x * 256 + threadIdx.x;
  if (idx >= A * 40) return;
  int a = idx / 40;
  int k8 = (idx - a * 40) * 8;
  bf16* dst = amsg + (size_t)a * HP + k8;
  if (k8 >= 304) {                    // pure pad: zeros
    uint4 z = {0, 0, 0, 0};
    *(uint4*)dst = z;
    return;
  }
  const int* p = a2b + (size_t)a * 6;
  uint4 u[6];
#pragma unroll
  for (int j = 0; j < 6; j++)
    u[j] = *(const uint4*)(msg + (size_t)p[j] * HP + k8);   // 16B aligned (HP row)
  float s[8] = {0.f,0.f,0.f,0.f,0.f,0.f,0.f,0.f};
#pragma unroll
  for (int j = 0; j < 6; j++) {
    unsigned w[4] = {u[j].x, u[j].y, u[j].z, u[j].w};
#pragma unroll
    for (int q2 = 0; q2 < 4; q2++) {
      union { unsigned u; float f; } lo, hi;
      lo.u = w[q2] << 16;
      hi.u = w[q2] & 0xffff0000u;
      s[2 * q2]     += lo.f;
      s[2 * q2 + 1] += hi.f;
    }
  }
  if (k8 == 296) { s[4] = s[5] = s[6] = s[7] = 0.f; }  // cols 300..303 -> 0
  short t[8];
#pragma unroll
  for (int j = 0; j < 8; j++) {
    union { bf16 b; short sh; } cv; cv.b = __float2bfloat16(s[j]); t[j] = cv.sh;
  }
  *(uint4*)dst = *(const uint4*)t;
}

// ============ slab-fetch gll MFMA GEMM: 64 rows x 320 cols, 4 waves split N ============
// K = 3 slabs x 5 steps (MODE0: 1 slab). Per slab each wave issues its row as
// 5 ADJACENT line-aligned glls (320B burst per random 640B-padded row). One
// barrier per slab. Issue order: B before G (B-waits never retire glls).
// MODE 0: C = fbb@Wi (5 steps);                          msg = relu(C), row0=0
// MODE 1: C = fbb@Wi + amsg[b2a]@Wh + (-msg[b2revb])@Wh; msg = relu(C), row0=0
// MODE 2: C = [fab | amsg]@Wo;                           hid = bf16(relu(C + bias))
// Epilogue writes ALL 320 cols (pad=0): full-line stores + pads stay zero.
template<int MODE>
__global__ __launch_bounds__(256)
void gemm_g(const bf16* __restrict__ FB, const bf16* __restrict__ WT,
            const int* __restrict__ b2a, const int* __restrict__ b2revb,
            const bf16* __restrict__ amsg, const bf16* __restrict__ msgc,
            const float* __restrict__ bias,
            bf16* __restrict__ msg_out, bf16* __restrict__ hid_out, int M)
{
  constexpr int KSTEPS = (MODE == 0) ? 5 : 15;
  constexpr bool DUAL = (MODE == 1);
  constexpr int NSLAB = (MODE == 0) ? 1 : 2;          // slab ring depth
  // vmcnt ledger:
  //   slab0 wait: newer than Gs0 = Gs1 glls        -> MODE1:10  MODE2:5  MODE0:0
  //   slab1 wait: newer than Gs1 = B2..B6          -> 25
  //   slab2 wait: newer than Gs2 = B8..B11         -> 20
  constexpr int W0C = (MODE == 1) ? 10 : (MODE == 2) ? 5 : 0;

  __shared__ __align__(16) short As[NSLAB * 5 * 2048];          // per step-slot 4KB
  __shared__ __align__(16) short Ms[DUAL ? NSLAB * 5 * 2048 : 16];

  const int tid = threadIdx.x;
  const int lane = tid & 63;
  const int wave = tid >> 6;
  const int gm0 = blockIdx.x * 64;

  // staging map: wave stages rows [wave*16, wave*16+16); LDS dest linear (gll),
  // swizzle applied on SOURCE k-chunk; read side applies same XOR.
  const int lrow = wave * 16 + (lane >> 2);
  const int ssl = (lane & 3) ^ ((lrow >> 1) & 3);
  const int grow = min(gm0 + lrow, M - 1);   // clamped (stores guarded)
  int ba = 0, rb = 0;
  if constexpr (DUAL) { ba = b2a[grow]; rb = b2revb[grow]; }

  // compute map
  const int r = lane & 15, q = lane >> 4;
  int aoff[4];
#pragma unroll
  for (int i = 0; i < 4; i++) {
    int rr = i * 16 + r;
    aoff[i] = rr * 32 + ((q ^ (rr >> 1)) & 3) * 8;
  }
  const bf16* bb = WT + (size_t)(wave * 80 + r) * KP + q * 8;

  f32x4 acc[4][5];
#pragma unroll
  for (int i = 0; i < 4; i++)
#pragma unroll
    for (int j = 0; j < 5; j++) acc[i][j] = (f32x4){0.f, 0.f, 0.f, 0.f};

  bf16x8 bufB[3][5];                 // ring of 3, distance-2 prefetch
  auto issueB = [&](int s) {
#pragma unroll
    for (int j = 0; j < 5; j++)
      bufB[s % 3][j] = *(const bf16x8*)(bb + (size_t)j * 16 * KP + s * 32);
  };

  // slab fetch: 5 adjacent LINE-ALIGNED 64B chunks of this wave's row(s)
  auto issueSlab = [&](int slab) {
    const int buf = slab % NSLAB;
    short* la = &As[buf * 5 * 2048 + wave * 512];
    if (slab == 0) {                 // head: feature row (exactly FBP*2 = 320B)
#pragma unroll
      for (int c = 0; c < 5; c++)
        gll16(la + c * 2048, FB + (size_t)grow * FBP + c * 32 + ssl * 8);
    } else {
      const int k0 = (slab - 1) * 160;   // tail k offset: slab1->0, slab2->160
      if constexpr (DUAL) {
#pragma unroll
        for (int c = 0; c < 5; c++)
          gll16(la + c * 2048, amsg + (size_t)ba * HP + k0 + c * 32 + ssl * 8);
        short* lm = &Ms[buf * 5 * 2048 + wave * 512];
#pragma unroll
        for (int c = 0; c < 5; c++)
          gll16(lm + c * 2048, msgc + (size_t)rb * HP + k0 + c * 32 + ssl * 8);
      } else {  // MODE 2
#pragma unroll
        for (int c = 0; c < 5; c++)
          gll16(la + c * 2048, amsg + (size_t)grow * HP + k0 + c * 32 + ssl * 8);
      }
    }
  };

  auto computeS = [&](int s) {
    const int buf = (s / 5) % NSLAB, c = s % 5;
    const short* ca = &As[(buf * 5 + c) * 2048];
    bf16x8 af[4];
#pragma unroll
    for (int i = 0; i < 4; i++) af[i] = *(const bf16x8*)(ca + aoff[i]);
    bf16x8 mfn[4];
    if constexpr (DUAL) {
      if (s >= 5) {
        const short* cm = &Ms[(buf * 5 + c) * 2048];
#pragma unroll
        for (int i = 0; i < 4; i++) {
          union { bf16x8 h; i32x4 w; } u;
          u.h = *(const bf16x8*)(cm + aoff[i]);
          u.w = u.w ^ (int)0x80008000;    // bf16 sign-flip: (-msg)@Wh
          mfn[i] = u.h;
        }
      }
    }
    __builtin_amdgcn_s_setprio(1);
#pragma unroll
    for (int j = 0; j < 5; j++)
#pragma unroll
      for (int i = 0; i < 4; i++) {
        acc[i][j] = __builtin_amdgcn_mfma_f32_16x16x32_bf16(af[i], bufB[s % 3][j], acc[i][j], 0, 0, 0);
        if constexpr (DUAL) {
          if (s >= 5)
            acc[i][j] = __builtin_amdgcn_mfma_f32_16x16x32_bf16(mfn[i], bufB[s % 3][j], acc[i][j], 0, 0, 0);
        }
      }
    __builtin_amdgcn_s_setprio(0);
  };

  // ---- prologue: B0, B1, Gs0, Gs1  (B BEFORE G: B-waits never retire glls) ----
  issueB(0);
  issueB(1);
  issueSlab(0);
  if (KSTEPS > 5) issueSlab(1);
  __builtin_amdgcn_sched_barrier(0);

  // ---- main loop: one vwait+barrier per slab; Gs2 issued after barrier@5 ----
#pragma unroll
  for (int s = 0; s < KSTEPS; s++) {
    if (s % 5 == 0) {
      __builtin_amdgcn_sched_barrier(0);   // pin: no B-issue sinks below the wait
      vwait(s == 0 ? W0C : (s == 5 ? 25 : 20));
      __builtin_amdgcn_s_barrier();
      __builtin_amdgcn_sched_barrier(0);
    }
    if (s + 2 < KSTEPS) issueB(s + 2);
    if (s == 5) {                          // issue slab2 (consumed at s=10)
      __builtin_amdgcn_sched_barrier(0);   // pin: B7 before Gs2
      issueSlab(2);
      __builtin_amdgcn_sched_barrier(0);   // pin: B8.. after Gs2
    }
    computeS(s);
  }

  // ---- epilogue: C/D frag col=lane&15, row=(lane>>4)*4+reg; write all 320 cols ----
#pragma unroll
  for (int j = 0; j < 5; j++) {
    int c = wave * 80 + j * 16 + r;        // < 320 always
    const bool pad = (c >= HH);
    float bia = (MODE == 2 && !pad) ? bias[c] : 0.f;
#pragma unroll
    for (int i = 0; i < 4; i++) {
#pragma unroll
      for (int ri = 0; ri < 4; ri++) {
        int g = gm0 + i * 16 + q * 4 + ri;
        if (g >= M) continue;
        float v = pad ? 0.f : acc[i][j][ri];
        if (MODE == 2) {
          hid_out[(size_t)g * HP + c] = __float2bfloat16(fmaxf(v + bia, 0.f));
        } else {
          float rv = fmaxf(v, 0.f);
          if (g == 0 || pad) rv = 0.f;
          msg_out[(size_t)g * HP + c] = __float2bfloat16(rv);
        }
      }
    }
  }
}

// per-molecule mean over sorted mol_id (binary search, no atomics); hid bf16, HP stride
__global__ void readout_k(const bf16* __restrict__ hid, const int* __restrict__ mol_id,
                          float* __restrict__ out, int A)
{
  __shared__ int bnd[2];
  int m = blockIdx.x;
  if (threadIdx.x < 2) {
    int target = m + (int)threadIdx.x;
    int lo = 0, hi = A;
    while (lo < hi) { int mid = (lo + hi) >> 1; if (mol_id[mid] < target) lo = mid + 1; else hi = mid; }
    bnd[threadIdx.x] = lo;
  }
  __syncthreads();
  int s = bnd[0], e = bnd[1];
  int h = threadIdx.x;
  if (h >= HH) return;
  float acc = 0.f;
  for (int a = s; a < e; a++) acc += __bfloat162float(hid[(size_t)a * HP + h]);
  int cnt = e - s; if (cnt < 1) cnt = 1;
  out[(size_t)m * HH + h] = acc / (float)cnt;
}

extern "C" void kernel_launch(void* const* d_in, const int* in_sizes, int n_in,
                              void* d_out, int out_size, void* d_ws, size_t ws_size,
                              hipStream_t stream)
{
  const float* f_atoms[2] = {(const float*)d_in[0], (const float*)d_in[2]};
  const float* f_bonds[2] = {(const float*)d_in[1], (const float*)d_in[3]};
  const float* W_i[2]     = {(const float*)d_in[4], (const float*)d_in[5]};
  const float* W_h[2]     = {(const float*)d_in[6], (const float*)d_in[7]};
  const float* W_o[2]     = {(const float*)d_in[8], (const float*)d_in[10]};
  const float* b_o[2]     = {(const float*)d_in[9], (const float*)d_in[11]};
  const int* a2b[2]    = {(const int*)d_in[12], (const int*)d_in[16]};
  const int* b2a[2]    = {(const int*)d_in[13], (const int*)d_in[17]};
  const int* b2revb[2] = {(const int*)d_in[14], (const int*)d_in[18]};
  const int* mol_id[2] = {(const int*)d_in[15], (const int*)d_in[19]};
  const int A = in_sizes[0] / AFD;   // 100001
  const int B = in_sizes[1] / BFD;   // 200001

  // ws: M0 | M1 (hid overlays) | amsg | fbb | fab | 4x WT  (~417 MB <= 422 proven)
  auto al = [](size_t x){ return (x + 255) & ~(size_t)255; };
  size_t r0 = al((size_t)B * HP * sizeof(bf16));
  size_t r1 = al((size_t)B * HP * sizeof(bf16));
  size_t amsz = al((size_t)A * HP * sizeof(bf16));
  size_t fbbsz = al((size_t)B * FBP * sizeof(bf16));
  size_t fabsz = al((size_t)A * FBP * sizeof(bf16));
  size_t wtsz = al((size_t)NWT * sizeof(bf16));
  if (ws_size < r0 + r1 + amsz + fbbsz + fabsz + 4 * wtsz) return;

  char* ws = (char*)d_ws;
  bf16*  M0  = (bf16*)ws;
  bf16*  M1  = (bf16*)(ws + r0);
  bf16*  hid = (bf16*)(ws + r0);            // overlays M1 region (bf16, A*HP)
  bf16*  amsg = (bf16*)(ws + r0 + r1);
  bf16*  fbb  = (bf16*)(ws + r0 + r1 + amsz);
  bf16*  fab  = (bf16*)(ws + r0 + r1 + amsz + fbbsz);
  size_t wofs = r0 + r1 + amsz + fbbsz + fabsz;
  bf16* WT1[2] = {(bf16*)(ws + wofs),            (bf16*)(ws + wofs + wtsz)};
  bf16* WT2[2] = {(bf16*)(ws + wofs + 2 * wtsz), (bf16*)(ws + wofs + 3 * wtsz)};

  dim3 blk(256);
  dim3 gW((NWT + 255) / 256);
  dim3 gB((B + 63) / 64);
  dim3 gA((A + 63) / 64);
  dim3 gG((A * 40 + 255) / 256);

  for (int p = 0; p < 2; p++) {
    build_wt<<<gW, blk, 0, stream>>>(W_i[p], W_h[p], BFD, WT1[p]);
    build_wt<<<gW, blk, 0, stream>>>(W_o[p], W_o[p] + (size_t)AFD * HH, AFD, WT2[p]);
  }

  for (int p = 0; p < 2; p++) {
    float* out_p = (float*)d_out + (size_t)p * NMOLS * HH;
    cvt_pad<<<(B * 20 + 255) / 256, blk, 0, stream>>>(f_bonds[p], BFD, fbb, B);
    cvt_pad<<<(A * 20 + 255) / 256, blk, 0, stream>>>(f_atoms[p], AFD, fab, A);
    // msg(M0) = relu(fbb @ W_i), row0=0  (pads zeroed by epilogue)
    gemm_g<0><<<gB, blk, 0, stream>>>(fbb, WT1[p], nullptr, nullptr,
                                      nullptr, nullptr, nullptr, M0, nullptr, B);
    // iter 1: amsg = gather6(M0); M1 = relu(fbb@Wi + amsg[b2a]@Wh - M0[b2revb]@Wh)
    gather6_k<<<gG, blk, 0, stream>>>(M0, a2b[p], amsg, A);
    gemm_g<1><<<gB, blk, 0, stream>>>(fbb, WT1[p], b2a[p], b2revb[p],
                                      amsg, M0, nullptr, M1, nullptr, B);
    // iter 2
    gather6_k<<<gG, blk, 0, stream>>>(M1, a2b[p], amsg, A);
    gemm_g<1><<<gB, blk, 0, stream>>>(fbb, WT1[p], b2a[p], b2revb[p],
                                      amsg, M1, nullptr, M0, nullptr, B);
    // output layer: hid(bf16) = relu([fab | gather6(M0)]@Wo + b)  (overlays M1)
    gather6_k<<<gG, blk, 0, stream>>>(M0, a2b[p], amsg, A);
    gemm_g<2><<<gA, blk, 0, stream>>>(fab, WT2[p], nullptr, nullptr,
                                      amsg, nullptr, b_o[p], nullptr, hid, A);
    // per-molecule mean readout
    readout_k<<<NMOLS, 320, 0, stream>>>(hid, mol_id[p], out_p, A);
  }
}